// Round 13
// baseline (340.769 us; speedup 1.0000x reference)
//
#include <hip/hip_runtime.h>
#include <hip/hip_bf16.h>

// 2-layer GCN (PyG GCNConv) on MI355X.
// R13: k_gemm2b rebuild. R12 counters: 40.6us, occ 8.6%, VALU 21% — LDS-pipe
// bound (0.31 ds-ops/MAC; 4 W2 b128 reads per 16 MACs). Now: 256 rows/block,
// thread = (rt=t&63 -> rows rt+64i, qj=wave-id -> j-group): W2s reads are
// wave-uniform broadcasts amortized over 4 rows x 8 j (0.125 LDS/MAC);
// t1s stride-33 b32 access = conflict-free. Everything else identical to R12.

#define IN_DIM 128
#define HID_DIM 64
#define OUT_DIM 32
#define BSHIFT 8
#define BSIZE 256
#define BMASK 255
#define PEB 4096      // edges per partition block
#define CAPSHIFT 13   // 8192 slots per bucket segment (expected max ~4500)

typedef __attribute__((ext_vector_type(2))) float v2f;

__device__ inline unsigned pack_bf16x2(float a, float b) {
    unsigned ua = __float_as_uint(a), ub = __float_as_uint(b);
    unsigned ra = (ua + 0x7fffu + ((ua >> 16) & 1u)) >> 16;        // RNE
    unsigned rb = (ub + 0x7fffu + ((ub >> 16) & 1u)) & 0xffff0000u;
    return (ra & 0xffffu) | rb;
}
#define BF_LO(w) __uint_as_float((w) << 16)
#define BF_HI(w) __uint_as_float((w) & 0xffff0000u)

__device__ inline v2f bfpair(unsigned u) {
    v2f r;
    r.x = __uint_as_float(u << 16);
    r.y = __uint_as_float(u & 0xffff0000u);
    return r;
}

#define ACC8(q)                                         \
    do {                                                \
        acc[0] += BF_LO((q).x); acc[1] += BF_HI((q).x); \
        acc[2] += BF_LO((q).y); acc[3] += BF_HI((q).y); \
        acc[4] += BF_LO((q).z); acc[5] += BF_HI((q).z); \
        acc[6] += BF_LO((q).w); acc[7] += BF_HI((q).w); \
    } while (0)

// ---------------------------------------------------------------- partition (single dispatch)
__global__ __launch_bounds__(256) void k_partition(const int* __restrict__ src,
                                                   const int* __restrict__ dst, int E,
                                                   int* __restrict__ bfill,
                                                   unsigned* __restrict__ packed, int B) {
    __shared__ int cnt[512];
    __shared__ int off[512];
    int t = threadIdx.x;
    for (int b = t; b < 512; b += 256) cnt[b] = 0;
    __syncthreads();
    int base = blockIdx.x * PEB;
#pragma unroll
    for (int i = 0; i < PEB / 256; ++i) {
        int e = base + i * 256 + t;
        if (e < E) atomicAdd(&cnt[dst[e] >> BSHIFT], 1);
    }
    __syncthreads();
    for (int b = t; b < B; b += 256) {
        int c = cnt[b];
        int o = c ? atomicAdd(&bfill[b], c) : 0;
        off[b] = (b << CAPSHIFT) + o;
    }
    __syncthreads();
#pragma unroll
    for (int i = 0; i < PEB / 256; ++i) {
        int e = base + i * 256 + t;
        if (e < E) {
            int d = dst[e];
            int s = src[e];
            int slot = atomicAdd(&off[d >> BSHIFT], 1);
            packed[slot] = ((unsigned)s << BSHIFT) | (unsigned)(d & BMASK);
        }
    }
}

// ---------------------------------------------------------------- per-bucket CSR build
__global__ __launch_bounds__(256) void k_csrfill(const unsigned* __restrict__ packed,
                                                 const int* __restrict__ bfill,
                                                 int* __restrict__ colidx,
                                                 uint2* __restrict__ rowptr2,
                                                 float* __restrict__ dinv,
                                                 int N, int B) {
    __shared__ int ldeg[256];
    __shared__ int lscan[256];
    __shared__ int sexc[256];
    __shared__ int lfill[256];
    int t = threadIdx.x, bkt = blockIdx.x;
    int base = bkt << CAPSHIFT;
    int end  = base + bfill[bkt];
    ldeg[t] = 0;
    __syncthreads();
    for (int e = base + t; e < end; e += 256)
        atomicAdd(&ldeg[packed[e] & BMASK], 1);
    __syncthreads();
    int v = ldeg[t];
    lscan[t] = v;
    __syncthreads();
    for (int off = 1; off < 256; off <<= 1) {
        int x = (t >= off) ? lscan[t - off] : 0;
        __syncthreads();
        lscan[t] += x;
        __syncthreads();
    }
    int exc = lscan[t] - v;
    sexc[t] = exc;
    lfill[t] = 0;
    int node = (bkt << BSHIFT) + t;
    if (node < N) {
        rowptr2[node] = make_uint2((unsigned)(base + exc), (unsigned)(base + exc + v));
        dinv[node] = rsqrtf((float)v + 1.0f);
    }
    __syncthreads();
    for (int e = base + t; e < end; e += 256) {
        unsigned w = packed[e];
        int ld = w & BMASK;
        int pos = base + sexc[ld] + atomicAdd(&lfill[ld], 1);
        colidx[pos] = (int)(w >> BSHIFT);
    }
}

// ---------------------------------------------------------------- GEMM1: g1b = bf16((x @ W1) * dinv)
__global__ __launch_bounds__(256) void k_gemm1(const float* __restrict__ x,
                                               const float* __restrict__ W,
                                               const float* __restrict__ dinv,
                                               unsigned* __restrict__ g1b, int N) {
    __shared__ float xs[64 * 36];
    __shared__ float ws[32 * 64];
    int t = threadIdx.x;
    int row0 = blockIdx.x * 64;
    int tx = t & 15;
    int ty = t >> 4;
    int sr = t >> 3, sc = t & 7;

    float acc[4][4] = {};
    for (int kt = 0; kt < 4; ++kt) {
        const float4* W4 = (const float4*)(W + kt * 32 * HID_DIM);
        float4* ws4 = (float4*)ws;
        ws4[t] = W4[t];
        ws4[t + 256] = W4[t + 256];
#pragma unroll
        for (int half = 0; half < 2; ++half) {
            int r = sr + half * 32;
            int row = row0 + r;
            float4 val = make_float4(0.f, 0.f, 0.f, 0.f);
            if (row < N)
                val = *(const float4*)&x[(size_t)row * IN_DIM + kt * 32 + sc * 4];
            *(float4*)&xs[r * 36 + sc * 4] = val;
        }
        __syncthreads();
#pragma unroll
        for (int k = 0; k < 32; k += 4) {
            float a[4][4], b[4][4];
#pragma unroll
            for (int i = 0; i < 4; ++i)
                *(float4*)a[i] = *(const float4*)&xs[(ty * 4 + i) * 36 + k];
#pragma unroll
            for (int kk = 0; kk < 4; ++kk)
                *(float4*)b[kk] = *(const float4*)&ws[(k + kk) * HID_DIM + tx * 4];
#pragma unroll
            for (int i = 0; i < 4; ++i)
#pragma unroll
                for (int kk = 0; kk < 4; ++kk)
#pragma unroll
                    for (int j = 0; j < 4; ++j)
                        acc[i][j] += a[i][kk] * b[kk][j];
        }
        __syncthreads();
    }
#pragma unroll
    for (int i = 0; i < 4; ++i) {
        int row = row0 + ty * 4 + i;
        if (row < N) {
            float dv = dinv[row];
            uint2 u;
            u.x = pack_bf16x2(acc[i][0] * dv, acc[i][1] * dv);
            u.y = pack_bf16x2(acc[i][2] * dv, acc[i][3] * dv);
            *(uint2*)&g1b[(size_t)row * 32 + tx * 2] = u;
        }
    }
}

// ---------------------------------------------------------------- agg layer 1
// 128 threads = 2 waves; node per 32-lane half (2 nodes/wave).
__global__ __launch_bounds__(128) void k_agg1(const unsigned* __restrict__ g1,
                                              const uint2* __restrict__ rowptr2,
                                              const int* __restrict__ colidx,
                                              const float* __restrict__ dinv,
                                              const float* __restrict__ b1,
                                              unsigned* __restrict__ t1b, int N) {
    int t = threadIdx.x;
    int lane = t & 63;
    int h = lane >> 5, hl = lane & 31;
    int grp = hl >> 3, fp = hl & 7;
    int dd = blockIdx.x * 4 + (t >> 6) * 2 + h;
    bool live = dd < N;
    int d = live ? dd : N - 1;

    uint2 be = rowptr2[d];
    v2f a01 = {0.f, 0.f}, a23 = {0.f, 0.f}, a45 = {0.f, 0.f}, a67 = {0.f, 0.f};
#define ACC8V(q)                                   \
    do {                                           \
        a01 += bfpair((q).x); a23 += bfpair((q).y);\
        a45 += bfpair((q).z); a67 += bfpair((q).w);\
    } while (0)
    int e = (int)be.x, end = (int)be.y;
    for (; e + 8 <= end; e += 8) {
        int s0 = colidx[e + grp];
        int s1 = colidx[e + 4 + grp];
        uint4 q0 = *(const uint4*)&g1[(size_t)s0 * 32 + fp * 4];
        uint4 q1 = *(const uint4*)&g1[(size_t)s1 * 32 + fp * 4];
        ACC8V(q0);
        ACC8V(q1);
    }
    for (; e + 4 <= end; e += 4) {
        int s = colidx[e + grp];
        uint4 q = *(const uint4*)&g1[(size_t)s * 32 + fp * 4];
        ACC8V(q);
    }
    if (e < end) {  // 1..3 edges left
        int cnt = end - e;
        int s = colidx[(grp < cnt) ? e + grp : e];
        uint4 q = *(const uint4*)&g1[(size_t)s * 32 + fp * 4];
        if (grp < cnt) ACC8V(q);
    }
#undef ACC8V
    float acc[8] = {a01.x, a01.y, a23.x, a23.y, a45.x, a45.y, a67.x, a67.y};
#pragma unroll
    for (int i = 0; i < 8; ++i) {
        acc[i] += __shfl_xor(acc[i], 8);
        acc[i] += __shfl_xor(acc[i], 16);
    }

    // self-loop + scale + bias + relu (per half)
    uint4 sq = *(const uint4*)&g1[(size_t)d * 32 + fp * 4];
    ACC8(sq);
    float dv = dinv[d];
    float4 bb0 = ((const float4*)b1)[fp * 2];
    float4 bb1 = ((const float4*)b1)[fp * 2 + 1];
    float v0 = fmaxf(dv * acc[0] + bb0.x, 0.f);
    float v1 = fmaxf(dv * acc[1] + bb0.y, 0.f);
    float v2 = fmaxf(dv * acc[2] + bb0.z, 0.f);
    float v3 = fmaxf(dv * acc[3] + bb0.w, 0.f);
    float v4 = fmaxf(dv * acc[4] + bb1.x, 0.f);
    float v5 = fmaxf(dv * acc[5] + bb1.y, 0.f);
    float v6 = fmaxf(dv * acc[6] + bb1.z, 0.f);
    float v7 = fmaxf(dv * acc[7] + bb1.w, 0.f);
    if (live && grp == 0) {
        uint4 u;
        u.x = pack_bf16x2(v0, v1);
        u.y = pack_bf16x2(v2, v3);
        u.z = pack_bf16x2(v4, v5);
        u.w = pack_bf16x2(v6, v7);
        *(uint4*)&t1b[(size_t)dd * 32 + fp * 4] = u;
    }
}

// ---------------------------------------------------------------- GEMM2: g2b = bf16((t1b @ W2) * dinv)
// 256 rows/block, 256 threads. rt = t&63 -> rows rt+64i; qj = wave id ->
// j = 8qj..8qj+7 (wave-uniform -> W2s reads are same-address broadcasts).
// t1s stride 33 (b32 access, banks (rt+kp)%32 -> free 2-way). LDS 41.8KB.
__global__ __launch_bounds__(256) void k_gemm2b(const unsigned* __restrict__ t1b,
                                                const float* __restrict__ W2,
                                                const float* __restrict__ dinv,
                                                unsigned* __restrict__ g2b, int N) {
    __shared__ unsigned t1s[256 * 33];      // 33.8 KB
    __shared__ float W2s[HID_DIM * OUT_DIM];  // 8 KB
    int t = threadIdx.x;
    int row0 = blockIdx.x * 256;

    const float4* W24 = (const float4*)W2;  // 512 float4
    float4* W2s4 = (float4*)W2s;
    W2s4[t] = W24[t];
    W2s4[t + 256] = W24[t + 256];
    // stage t1b: 2048 uint4 -> 8/thread; scatter to stride-33 rows as 4x b32
#pragma unroll
    for (int i = 0; i < 8; ++i) {
        int idx4 = t + 256 * i;
        int row = idx4 >> 3, c4 = idx4 & 7;
        int grow = row0 + row;
        uint4 q = make_uint4(0u, 0u, 0u, 0u);
        if (grow < N) q = *(const uint4*)&t1b[(size_t)grow * 32 + c4 * 4];
        unsigned* dp = &t1s[row * 33 + c4 * 4];
        dp[0] = q.x; dp[1] = q.y; dp[2] = q.z; dp[3] = q.w;
    }
    __syncthreads();

    int rt = t & 63;        // row within 64-row group
    int qj = t >> 6;        // wave id = j-group (wave-uniform)
    const float* wb = &W2s[qj * 8];
    float acc[4][8] = {};
#pragma unroll
    for (int kp = 0; kp < 32; ++kp) {
        float4 wl0 = *(const float4*)&wb[(2 * kp) * OUT_DIM];
        float4 wl1 = *(const float4*)&wb[(2 * kp) * OUT_DIM + 4];
        float4 wh0 = *(const float4*)&wb[(2 * kp + 1) * OUT_DIM];
        float4 wh1 = *(const float4*)&wb[(2 * kp + 1) * OUT_DIM + 4];
#pragma unroll
        for (int i = 0; i < 4; ++i) {
            unsigned u = t1s[(rt + 64 * i) * 33 + kp];
            float a0 = BF_LO(u), a1 = BF_HI(u);
            acc[i][0] += a0 * wl0.x + a1 * wh0.x;
            acc[i][1] += a0 * wl0.y + a1 * wh0.y;
            acc[i][2] += a0 * wl0.z + a1 * wh0.z;
            acc[i][3] += a0 * wl0.w + a1 * wh0.w;
            acc[i][4] += a0 * wl1.x + a1 * wh1.x;
            acc[i][5] += a0 * wl1.y + a1 * wh1.y;
            acc[i][6] += a0 * wl1.z + a1 * wh1.z;
            acc[i][7] += a0 * wl1.w + a1 * wh1.w;
        }
    }
#pragma unroll
    for (int i = 0; i < 4; ++i) {
        int row = row0 + rt + 64 * i;
        if (row < N) {
            float dv = dinv[row];
            uint4 u;
            u.x = pack_bf16x2(acc[i][0] * dv, acc[i][1] * dv);
            u.y = pack_bf16x2(acc[i][2] * dv, acc[i][3] * dv);
            u.z = pack_bf16x2(acc[i][4] * dv, acc[i][5] * dv);
            u.w = pack_bf16x2(acc[i][6] * dv, acc[i][7] * dv);
            *(uint4*)&g2b[(size_t)row * 16 + qj * 4] = u;
        }
    }
}

// ---------------------------------------------------------------- agg layer 2
// 128 threads = 2 waves; node per 16-lane quarter (4 nodes/wave).
__global__ __launch_bounds__(128) void k_agg2(const unsigned* __restrict__ g2,
                                              const uint2* __restrict__ rowptr2,
                                              const int* __restrict__ colidx,
                                              const float* __restrict__ dinv,
                                              const float* __restrict__ b2,
                                              float* __restrict__ out, int N) {
    int t = threadIdx.x;
    int lane = t & 63;
    int qd = lane >> 4, ql = lane & 15;
    int grp = ql >> 2, fp = ql & 3;
    int dd = blockIdx.x * 8 + (t >> 6) * 4 + qd;
    bool live = dd < N;
    int d = live ? dd : N - 1;

    uint2 be = rowptr2[d];
    v2f a01 = {0.f, 0.f}, a23 = {0.f, 0.f}, a45 = {0.f, 0.f}, a67 = {0.f, 0.f};
#define ACC8V(q)                                   \
    do {                                           \
        a01 += bfpair((q).x); a23 += bfpair((q).y);\
        a45 += bfpair((q).z); a67 += bfpair((q).w);\
    } while (0)
    int e = (int)be.x, end = (int)be.y;
    for (; e + 8 <= end; e += 8) {
        int s0 = colidx[e + grp];
        int s1 = colidx[e + 4 + grp];
        uint4 q0 = *(const uint4*)&g2[(size_t)s0 * 16 + fp * 4];
        uint4 q1 = *(const uint4*)&g2[(size_t)s1 * 16 + fp * 4];
        ACC8V(q0);
        ACC8V(q1);
    }
    for (; e + 4 <= end; e += 4) {
        int s = colidx[e + grp];
        uint4 q = *(const uint4*)&g2[(size_t)s * 16 + fp * 4];
        ACC8V(q);
    }
    if (e < end) {  // 1..3 edges left
        int cnt = end - e;
        int s = colidx[(grp < cnt) ? e + grp : e];
        uint4 q = *(const uint4*)&g2[(size_t)s * 16 + fp * 4];
        if (grp < cnt) ACC8V(q);
    }
#undef ACC8V
    float acc[8] = {a01.x, a01.y, a23.x, a23.y, a45.x, a45.y, a67.x, a67.y};
#pragma unroll
    for (int i = 0; i < 8; ++i) {
        acc[i] += __shfl_xor(acc[i], 4);
        acc[i] += __shfl_xor(acc[i], 8);
    }
    // self-loop + epilogue (per quarter)
    uint4 sq = *(const uint4*)&g2[(size_t)d * 16 + fp * 4];
    ACC8(sq);
    float dv = dinv[d];
    float4 bb0 = ((const float4*)b2)[fp * 2];
    float4 bb1 = ((const float4*)b2)[fp * 2 + 1];
    if (live && grp == 0) {
        float4 r0, r1;
        r0.x = dv * acc[0] + bb0.x; r0.y = dv * acc[1] + bb0.y;
        r0.z = dv * acc[2] + bb0.z; r0.w = dv * acc[3] + bb0.w;
        r1.x = dv * acc[4] + bb1.x; r1.y = dv * acc[5] + bb1.y;
        r1.z = dv * acc[6] + bb1.z; r1.w = dv * acc[7] + bb1.w;
        *(float4*)&out[(size_t)dd * OUT_DIM + fp * 8] = r0;
        *(float4*)&out[(size_t)dd * OUT_DIM + fp * 8 + 4] = r1;
    }
}

// ---------------------------------------------------------------- launch
extern "C" void kernel_launch(void* const* d_in, const int* in_sizes, int n_in,
                              void* d_out, int out_size, void* d_ws, size_t ws_size,
                              hipStream_t stream) {
    const float* x  = (const float*)d_in[0];
    const int*   ei = (const int*)d_in[1];
    const float* W1 = (const float*)d_in[2];
    const float* b1 = (const float*)d_in[3];
    const float* W2 = (const float*)d_in[4];
    const float* b2 = (const float*)d_in[5];
    float* out = (float*)d_out;

    const int N = in_sizes[0] / IN_DIM;
    const int E = in_sizes[1] / 2;
    const int* src = ei;
    const int* dst = ei + E;

    const int B   = (N + BSIZE - 1) / BSIZE;          // buckets
    const int nPB = (E + PEB - 1) / PEB;              // partition blocks
    const size_t SLOTS = (size_t)B << CAPSHIFT;       // segmented edge slots

    char* p = (char*)d_ws;
    auto alloc = [&](size_t bytes) -> void* {
        void* r = (void*)p;
        p += (bytes + 255) & ~(size_t)255;
        return r;
    };
    int*      bfill   = (int*)alloc((size_t)B * 4);
    unsigned* packed  = (unsigned*)alloc(SLOTS * 4);
    int*      colidx  = (int*)alloc(SLOTS * 4);
    uint2*    rowptr2 = (uint2*)alloc((size_t)N * 8);
    float*    dinv    = (float*)alloc((size_t)N * 4);
    unsigned* g1b     = (unsigned*)alloc((size_t)N * 32 * 4);  // bf16x2 x 32/row
    unsigned* t1b     = (unsigned*)alloc((size_t)N * 32 * 4);  // bf16x2 x 32/row
    unsigned* g2b     = (unsigned*)alloc((size_t)N * 16 * 4);  // bf16x2 x 16/row

    hipMemsetAsync(bfill, 0, (size_t)B * 4, stream);
    k_partition<<<nPB, 256, 0, stream>>>(src, dst, E, bfill, packed, B);
    k_csrfill<<<B, 256, 0, stream>>>(packed, bfill, colidx, rowptr2, dinv, N, B);

    k_gemm1<<<(N + 63) / 64, 256, 0, stream>>>(x, W1, dinv, g1b, N);
    k_agg1<<<(N + 3) / 4, 128, 0, stream>>>(g1b, rowptr2, colidx, dinv, b1, t1b, N);
    k_gemm2b<<<(N + 255) / 256, 256, 0, stream>>>(t1b, W2, dinv, g2b, N);
    k_agg2<<<(N + 7) / 8, 128, 0, stream>>>(g2b, rowptr2, colidx, dinv, b2, out, N);
}

// Round 14
// 235.128 us; speedup vs baseline: 1.4493x; 1.4493x over previous
//
#include <hip/hip_runtime.h>
#include <hip/hip_bf16.h>

// 2-layer GCN (PyG GCNConv) on MI355X.
// R14: revert R13's gemm2b (VGPR 256 + 90MB spill traffic). New gemm2b uses
// the proven gemm1 shape: t1 unpacked to fp32 at staging (no per-read unpack
// in the inner loop), 2x4 micro-tile, pure b128+fma loop, #pragma unroll 4
// to cap register pressure. R12's real gemm2b problem was latency (VGPR 140
// -> 3 waves/SIMD, dependent b32+unpack chain). Everything else = R12.

#define IN_DIM 128
#define HID_DIM 64
#define OUT_DIM 32
#define BSHIFT 8
#define BSIZE 256
#define BMASK 255
#define PEB 4096      // edges per partition block
#define CAPSHIFT 13   // 8192 slots per bucket segment (expected max ~4500)

typedef __attribute__((ext_vector_type(2))) float v2f;

__device__ inline unsigned pack_bf16x2(float a, float b) {
    unsigned ua = __float_as_uint(a), ub = __float_as_uint(b);
    unsigned ra = (ua + 0x7fffu + ((ua >> 16) & 1u)) >> 16;        // RNE
    unsigned rb = (ub + 0x7fffu + ((ub >> 16) & 1u)) & 0xffff0000u;
    return (ra & 0xffffu) | rb;
}
#define BF_LO(w) __uint_as_float((w) << 16)
#define BF_HI(w) __uint_as_float((w) & 0xffff0000u)

__device__ inline v2f bfpair(unsigned u) {
    v2f r;
    r.x = __uint_as_float(u << 16);
    r.y = __uint_as_float(u & 0xffff0000u);
    return r;
}

#define ACC8(q)                                         \
    do {                                                \
        acc[0] += BF_LO((q).x); acc[1] += BF_HI((q).x); \
        acc[2] += BF_LO((q).y); acc[3] += BF_HI((q).y); \
        acc[4] += BF_LO((q).z); acc[5] += BF_HI((q).z); \
        acc[6] += BF_LO((q).w); acc[7] += BF_HI((q).w); \
    } while (0)

// ---------------------------------------------------------------- partition (single dispatch)
__global__ __launch_bounds__(256) void k_partition(const int* __restrict__ src,
                                                   const int* __restrict__ dst, int E,
                                                   int* __restrict__ bfill,
                                                   unsigned* __restrict__ packed, int B) {
    __shared__ int cnt[512];
    __shared__ int off[512];
    int t = threadIdx.x;
    for (int b = t; b < 512; b += 256) cnt[b] = 0;
    __syncthreads();
    int base = blockIdx.x * PEB;
#pragma unroll
    for (int i = 0; i < PEB / 256; ++i) {
        int e = base + i * 256 + t;
        if (e < E) atomicAdd(&cnt[dst[e] >> BSHIFT], 1);
    }
    __syncthreads();
    for (int b = t; b < B; b += 256) {
        int c = cnt[b];
        int o = c ? atomicAdd(&bfill[b], c) : 0;
        off[b] = (b << CAPSHIFT) + o;
    }
    __syncthreads();
#pragma unroll
    for (int i = 0; i < PEB / 256; ++i) {
        int e = base + i * 256 + t;
        if (e < E) {
            int d = dst[e];
            int s = src[e];
            int slot = atomicAdd(&off[d >> BSHIFT], 1);
            packed[slot] = ((unsigned)s << BSHIFT) | (unsigned)(d & BMASK);
        }
    }
}

// ---------------------------------------------------------------- per-bucket CSR build
__global__ __launch_bounds__(256) void k_csrfill(const unsigned* __restrict__ packed,
                                                 const int* __restrict__ bfill,
                                                 int* __restrict__ colidx,
                                                 uint2* __restrict__ rowptr2,
                                                 float* __restrict__ dinv,
                                                 int N, int B) {
    __shared__ int ldeg[256];
    __shared__ int lscan[256];
    __shared__ int sexc[256];
    __shared__ int lfill[256];
    int t = threadIdx.x, bkt = blockIdx.x;
    int base = bkt << CAPSHIFT;
    int end  = base + bfill[bkt];
    ldeg[t] = 0;
    __syncthreads();
    for (int e = base + t; e < end; e += 256)
        atomicAdd(&ldeg[packed[e] & BMASK], 1);
    __syncthreads();
    int v = ldeg[t];
    lscan[t] = v;
    __syncthreads();
    for (int off = 1; off < 256; off <<= 1) {
        int x = (t >= off) ? lscan[t - off] : 0;
        __syncthreads();
        lscan[t] += x;
        __syncthreads();
    }
    int exc = lscan[t] - v;
    sexc[t] = exc;
    lfill[t] = 0;
    int node = (bkt << BSHIFT) + t;
    if (node < N) {
        rowptr2[node] = make_uint2((unsigned)(base + exc), (unsigned)(base + exc + v));
        dinv[node] = rsqrtf((float)v + 1.0f);
    }
    __syncthreads();
    for (int e = base + t; e < end; e += 256) {
        unsigned w = packed[e];
        int ld = w & BMASK;
        int pos = base + sexc[ld] + atomicAdd(&lfill[ld], 1);
        colidx[pos] = (int)(w >> BSHIFT);
    }
}

// ---------------------------------------------------------------- GEMM1: g1b = bf16((x @ W1) * dinv)
__global__ __launch_bounds__(256) void k_gemm1(const float* __restrict__ x,
                                               const float* __restrict__ W,
                                               const float* __restrict__ dinv,
                                               unsigned* __restrict__ g1b, int N) {
    __shared__ float xs[64 * 36];
    __shared__ float ws[32 * 64];
    int t = threadIdx.x;
    int row0 = blockIdx.x * 64;
    int tx = t & 15;
    int ty = t >> 4;
    int sr = t >> 3, sc = t & 7;

    float acc[4][4] = {};
    for (int kt = 0; kt < 4; ++kt) {
        const float4* W4 = (const float4*)(W + kt * 32 * HID_DIM);
        float4* ws4 = (float4*)ws;
        ws4[t] = W4[t];
        ws4[t + 256] = W4[t + 256];
#pragma unroll
        for (int half = 0; half < 2; ++half) {
            int r = sr + half * 32;
            int row = row0 + r;
            float4 val = make_float4(0.f, 0.f, 0.f, 0.f);
            if (row < N)
                val = *(const float4*)&x[(size_t)row * IN_DIM + kt * 32 + sc * 4];
            *(float4*)&xs[r * 36 + sc * 4] = val;
        }
        __syncthreads();
#pragma unroll
        for (int k = 0; k < 32; k += 4) {
            float a[4][4], b[4][4];
#pragma unroll
            for (int i = 0; i < 4; ++i)
                *(float4*)a[i] = *(const float4*)&xs[(ty * 4 + i) * 36 + k];
#pragma unroll
            for (int kk = 0; kk < 4; ++kk)
                *(float4*)b[kk] = *(const float4*)&ws[(k + kk) * HID_DIM + tx * 4];
#pragma unroll
            for (int i = 0; i < 4; ++i)
#pragma unroll
                for (int kk = 0; kk < 4; ++kk)
#pragma unroll
                    for (int j = 0; j < 4; ++j)
                        acc[i][j] += a[i][kk] * b[kk][j];
        }
        __syncthreads();
    }
#pragma unroll
    for (int i = 0; i < 4; ++i) {
        int row = row0 + ty * 4 + i;
        if (row < N) {
            float dv = dinv[row];
            uint2 u;
            u.x = pack_bf16x2(acc[i][0] * dv, acc[i][1] * dv);
            u.y = pack_bf16x2(acc[i][2] * dv, acc[i][3] * dv);
            *(uint2*)&g1b[(size_t)row * 32 + tx * 2] = u;
        }
    }
}

// ---------------------------------------------------------------- agg layer 1
// 128 threads = 2 waves; node per 32-lane half (2 nodes/wave).
__global__ __launch_bounds__(128) void k_agg1(const unsigned* __restrict__ g1,
                                              const uint2* __restrict__ rowptr2,
                                              const int* __restrict__ colidx,
                                              const float* __restrict__ dinv,
                                              const float* __restrict__ b1,
                                              unsigned* __restrict__ t1b, int N) {
    int t = threadIdx.x;
    int lane = t & 63;
    int h = lane >> 5, hl = lane & 31;
    int grp = hl >> 3, fp = hl & 7;
    int dd = blockIdx.x * 4 + (t >> 6) * 2 + h;
    bool live = dd < N;
    int d = live ? dd : N - 1;

    uint2 be = rowptr2[d];
    v2f a01 = {0.f, 0.f}, a23 = {0.f, 0.f}, a45 = {0.f, 0.f}, a67 = {0.f, 0.f};
#define ACC8V(q)                                   \
    do {                                           \
        a01 += bfpair((q).x); a23 += bfpair((q).y);\
        a45 += bfpair((q).z); a67 += bfpair((q).w);\
    } while (0)
    int e = (int)be.x, end = (int)be.y;
    for (; e + 8 <= end; e += 8) {
        int s0 = colidx[e + grp];
        int s1 = colidx[e + 4 + grp];
        uint4 q0 = *(const uint4*)&g1[(size_t)s0 * 32 + fp * 4];
        uint4 q1 = *(const uint4*)&g1[(size_t)s1 * 32 + fp * 4];
        ACC8V(q0);
        ACC8V(q1);
    }
    for (; e + 4 <= end; e += 4) {
        int s = colidx[e + grp];
        uint4 q = *(const uint4*)&g1[(size_t)s * 32 + fp * 4];
        ACC8V(q);
    }
    if (e < end) {  // 1..3 edges left
        int cnt = end - e;
        int s = colidx[(grp < cnt) ? e + grp : e];
        uint4 q = *(const uint4*)&g1[(size_t)s * 32 + fp * 4];
        if (grp < cnt) ACC8V(q);
    }
#undef ACC8V
    float acc[8] = {a01.x, a01.y, a23.x, a23.y, a45.x, a45.y, a67.x, a67.y};
#pragma unroll
    for (int i = 0; i < 8; ++i) {
        acc[i] += __shfl_xor(acc[i], 8);
        acc[i] += __shfl_xor(acc[i], 16);
    }

    // self-loop + scale + bias + relu (per half)
    uint4 sq = *(const uint4*)&g1[(size_t)d * 32 + fp * 4];
    ACC8(sq);
    float dv = dinv[d];
    float4 bb0 = ((const float4*)b1)[fp * 2];
    float4 bb1 = ((const float4*)b1)[fp * 2 + 1];
    float v0 = fmaxf(dv * acc[0] + bb0.x, 0.f);
    float v1 = fmaxf(dv * acc[1] + bb0.y, 0.f);
    float v2 = fmaxf(dv * acc[2] + bb0.z, 0.f);
    float v3 = fmaxf(dv * acc[3] + bb0.w, 0.f);
    float v4 = fmaxf(dv * acc[4] + bb1.x, 0.f);
    float v5 = fmaxf(dv * acc[5] + bb1.y, 0.f);
    float v6 = fmaxf(dv * acc[6] + bb1.z, 0.f);
    float v7 = fmaxf(dv * acc[7] + bb1.w, 0.f);
    if (live && grp == 0) {
        uint4 u;
        u.x = pack_bf16x2(v0, v1);
        u.y = pack_bf16x2(v2, v3);
        u.z = pack_bf16x2(v4, v5);
        u.w = pack_bf16x2(v6, v7);
        *(uint4*)&t1b[(size_t)dd * 32 + fp * 4] = u;
    }
}

// ---------------------------------------------------------------- GEMM2: g2b = bf16((t1b @ W2) * dinv)
// gemm1-shape rebuild: 64 rows/block, t1 unpacked to fp32 at staging
// (t1s 64x68, 17KB; W2s 8KB). ty = t>>3 -> rows 2ty..2ty+1, tx = t&7 ->
// cols 4tx..4tx+3. Inner loop: pure ds_read_b128 + fma, unroll 4.
// a-reads 2-way aliased (free), b-reads same-address broadcast (free).
__global__ __launch_bounds__(256) void k_gemm2b(const unsigned* __restrict__ t1b,
                                                const float* __restrict__ W2,
                                                const float* __restrict__ dinv,
                                                unsigned* __restrict__ g2b, int N) {
    __shared__ float t1s[64 * 68];            // fp32, stride 68
    __shared__ float W2s[HID_DIM * OUT_DIM];  // 8 KB
    int t = threadIdx.x;
    int row0 = blockIdx.x * 64;

    const float4* W24 = (const float4*)W2;  // 512 float4
    float4* W2s4 = (float4*)W2s;
    W2s4[t] = W24[t];
    W2s4[t + 256] = W24[t + 256];
    // stage t1b -> fp32: 2048 uints, 8/thread, unpack to float2
#pragma unroll
    for (int i = 0; i < 8; ++i) {
        int idx = t + 256 * i;
        int r = idx >> 5, c = idx & 31;
        int grow = row0 + r;
        unsigned u = 0;
        if (grow < N) u = t1b[(size_t)grow * 32 + c];
        float2 f;
        f.x = BF_LO(u);
        f.y = BF_HI(u);
        *(float2*)&t1s[r * 68 + c * 2] = f;
    }
    __syncthreads();

    int ty = t >> 3;   // 32 groups x 2 rows
    int tx = t & 7;    // 8 groups x 4 cols
    float acc[2][4] = {};
#pragma unroll 4
    for (int k = 0; k < 64; k += 4) {
        float a[2][4], b[4][4];
#pragma unroll
        for (int i = 0; i < 2; ++i)
            *(float4*)a[i] = *(const float4*)&t1s[(ty * 2 + i) * 68 + k];
#pragma unroll
        for (int kk = 0; kk < 4; ++kk)
            *(float4*)b[kk] = *(const float4*)&W2s[(k + kk) * OUT_DIM + tx * 4];
#pragma unroll
        for (int i = 0; i < 2; ++i)
#pragma unroll
            for (int kk = 0; kk < 4; ++kk)
#pragma unroll
                for (int j = 0; j < 4; ++j)
                    acc[i][j] += a[i][kk] * b[kk][j];
    }
#pragma unroll
    for (int i = 0; i < 2; ++i) {
        int row = row0 + ty * 2 + i;
        if (row < N) {
            float dv = dinv[row];
            uint2 u;
            u.x = pack_bf16x2(acc[i][0] * dv, acc[i][1] * dv);
            u.y = pack_bf16x2(acc[i][2] * dv, acc[i][3] * dv);
            *(uint2*)&g2b[(size_t)row * 16 + tx * 2] = u;
        }
    }
}

// ---------------------------------------------------------------- agg layer 2
// 128 threads = 2 waves; node per 16-lane quarter (4 nodes/wave).
__global__ __launch_bounds__(128) void k_agg2(const unsigned* __restrict__ g2,
                                              const uint2* __restrict__ rowptr2,
                                              const int* __restrict__ colidx,
                                              const float* __restrict__ dinv,
                                              const float* __restrict__ b2,
                                              float* __restrict__ out, int N) {
    int t = threadIdx.x;
    int lane = t & 63;
    int qd = lane >> 4, ql = lane & 15;
    int grp = ql >> 2, fp = ql & 3;
    int dd = blockIdx.x * 8 + (t >> 6) * 4 + qd;
    bool live = dd < N;
    int d = live ? dd : N - 1;

    uint2 be = rowptr2[d];
    v2f a01 = {0.f, 0.f}, a23 = {0.f, 0.f}, a45 = {0.f, 0.f}, a67 = {0.f, 0.f};
#define ACC8V(q)                                   \
    do {                                           \
        a01 += bfpair((q).x); a23 += bfpair((q).y);\
        a45 += bfpair((q).z); a67 += bfpair((q).w);\
    } while (0)
    int e = (int)be.x, end = (int)be.y;
    for (; e + 8 <= end; e += 8) {
        int s0 = colidx[e + grp];
        int s1 = colidx[e + 4 + grp];
        uint4 q0 = *(const uint4*)&g2[(size_t)s0 * 16 + fp * 4];
        uint4 q1 = *(const uint4*)&g2[(size_t)s1 * 16 + fp * 4];
        ACC8V(q0);
        ACC8V(q1);
    }
    for (; e + 4 <= end; e += 4) {
        int s = colidx[e + grp];
        uint4 q = *(const uint4*)&g2[(size_t)s * 16 + fp * 4];
        ACC8V(q);
    }
    if (e < end) {  // 1..3 edges left
        int cnt = end - e;
        int s = colidx[(grp < cnt) ? e + grp : e];
        uint4 q = *(const uint4*)&g2[(size_t)s * 16 + fp * 4];
        if (grp < cnt) ACC8V(q);
    }
#undef ACC8V
    float acc[8] = {a01.x, a01.y, a23.x, a23.y, a45.x, a45.y, a67.x, a67.y};
#pragma unroll
    for (int i = 0; i < 8; ++i) {
        acc[i] += __shfl_xor(acc[i], 4);
        acc[i] += __shfl_xor(acc[i], 8);
    }
    // self-loop + epilogue (per quarter)
    uint4 sq = *(const uint4*)&g2[(size_t)d * 16 + fp * 4];
    ACC8(sq);
    float dv = dinv[d];
    float4 bb0 = ((const float4*)b2)[fp * 2];
    float4 bb1 = ((const float4*)b2)[fp * 2 + 1];
    if (live && grp == 0) {
        float4 r0, r1;
        r0.x = dv * acc[0] + bb0.x; r0.y = dv * acc[1] + bb0.y;
        r0.z = dv * acc[2] + bb0.z; r0.w = dv * acc[3] + bb0.w;
        r1.x = dv * acc[4] + bb1.x; r1.y = dv * acc[5] + bb1.y;
        r1.z = dv * acc[6] + bb1.z; r1.w = dv * acc[7] + bb1.w;
        *(float4*)&out[(size_t)dd * OUT_DIM + fp * 8] = r0;
        *(float4*)&out[(size_t)dd * OUT_DIM + fp * 8 + 4] = r1;
    }
}

// ---------------------------------------------------------------- launch
extern "C" void kernel_launch(void* const* d_in, const int* in_sizes, int n_in,
                              void* d_out, int out_size, void* d_ws, size_t ws_size,
                              hipStream_t stream) {
    const float* x  = (const float*)d_in[0];
    const int*   ei = (const int*)d_in[1];
    const float* W1 = (const float*)d_in[2];
    const float* b1 = (const float*)d_in[3];
    const float* W2 = (const float*)d_in[4];
    const float* b2 = (const float*)d_in[5];
    float* out = (float*)d_out;

    const int N = in_sizes[0] / IN_DIM;
    const int E = in_sizes[1] / 2;
    const int* src = ei;
    const int* dst = ei + E;

    const int B   = (N + BSIZE - 1) / BSIZE;          // buckets
    const int nPB = (E + PEB - 1) / PEB;              // partition blocks
    const size_t SLOTS = (size_t)B << CAPSHIFT;       // segmented edge slots

    char* p = (char*)d_ws;
    auto alloc = [&](size_t bytes) -> void* {
        void* r = (void*)p;
        p += (bytes + 255) & ~(size_t)255;
        return r;
    };
    int*      bfill   = (int*)alloc((size_t)B * 4);
    unsigned* packed  = (unsigned*)alloc(SLOTS * 4);
    int*      colidx  = (int*)alloc(SLOTS * 4);
    uint2*    rowptr2 = (uint2*)alloc((size_t)N * 8);
    float*    dinv    = (float*)alloc((size_t)N * 4);
    unsigned* g1b     = (unsigned*)alloc((size_t)N * 32 * 4);  // bf16x2 x 32/row
    unsigned* t1b     = (unsigned*)alloc((size_t)N * 32 * 4);  // bf16x2 x 32/row
    unsigned* g2b     = (unsigned*)alloc((size_t)N * 16 * 4);  // bf16x2 x 16/row

    hipMemsetAsync(bfill, 0, (size_t)B * 4, stream);
    k_partition<<<nPB, 256, 0, stream>>>(src, dst, E, bfill, packed, B);
    k_csrfill<<<B, 256, 0, stream>>>(packed, bfill, colidx, rowptr2, dinv, N, B);

    k_gemm1<<<(N + 63) / 64, 256, 0, stream>>>(x, W1, dinv, g1b, N);
    k_agg1<<<(N + 3) / 4, 128, 0, stream>>>(g1b, rowptr2, colidx, dinv, b1, t1b, N);
    k_gemm2b<<<(N + 63) / 64, 256, 0, stream>>>(t1b, W2, dinv, g2b, N);
    k_agg2<<<(N + 7) / 8, 128, 0, stream>>>(g2b, rowptr2, colidx, dinv, b2, out, N);
}

// Round 15
// 233.990 us; speedup vs baseline: 1.4563x; 1.0049x over previous
//
#include <hip/hip_runtime.h>
#include <hip/hip_bf16.h>

// 2-layer GCN (PyG GCNConv) on MI355X.
// R15: deeper node-per-wave packing (R12's amortization axis, one more step):
//   k_agg1: 4 nodes/wave (16-lane quarter: grp 0..1, fp 0..7, uint4 rows) —
//           reduce 2 levels -> 1, fixed cost /2.
//   k_agg2: 8 nodes/wave (8-lane octet: grp 0..1, fp 0..3) — reduce 1 level.
//   k_partition: dst values cached in VGPRs across the two passes.
// Everything else identical to R14 (235us; top-5 all harness poison fills).

#define IN_DIM 128
#define HID_DIM 64
#define OUT_DIM 32
#define BSHIFT 8
#define BSIZE 256
#define BMASK 255
#define PEB 4096      // edges per partition block
#define CAPSHIFT 13   // 8192 slots per bucket segment (expected max ~4500)

typedef __attribute__((ext_vector_type(2))) float v2f;

__device__ inline unsigned pack_bf16x2(float a, float b) {
    unsigned ua = __float_as_uint(a), ub = __float_as_uint(b);
    unsigned ra = (ua + 0x7fffu + ((ua >> 16) & 1u)) >> 16;        // RNE
    unsigned rb = (ub + 0x7fffu + ((ub >> 16) & 1u)) & 0xffff0000u;
    return (ra & 0xffffu) | rb;
}
#define BF_LO(w) __uint_as_float((w) << 16)
#define BF_HI(w) __uint_as_float((w) & 0xffff0000u)

__device__ inline v2f bfpair(unsigned u) {
    v2f r;
    r.x = __uint_as_float(u << 16);
    r.y = __uint_as_float(u & 0xffff0000u);
    return r;
}

#define ACC8(q)                                         \
    do {                                                \
        acc[0] += BF_LO((q).x); acc[1] += BF_HI((q).x); \
        acc[2] += BF_LO((q).y); acc[3] += BF_HI((q).y); \
        acc[4] += BF_LO((q).z); acc[5] += BF_HI((q).z); \
        acc[6] += BF_LO((q).w); acc[7] += BF_HI((q).w); \
    } while (0)

// ---------------------------------------------------------------- partition (single dispatch)
__global__ __launch_bounds__(256) void k_partition(const int* __restrict__ src,
                                                   const int* __restrict__ dst, int E,
                                                   int* __restrict__ bfill,
                                                   unsigned* __restrict__ packed, int B) {
    __shared__ int cnt[512];
    __shared__ int off[512];
    int t = threadIdx.x;
    for (int b = t; b < 512; b += 256) cnt[b] = 0;
    __syncthreads();
    int base = blockIdx.x * PEB;
    int dv[PEB / 256];  // cache dst values across passes
#pragma unroll
    for (int i = 0; i < PEB / 256; ++i) {
        int e = base + i * 256 + t;
        dv[i] = (e < E) ? dst[e] : -1;
        if (dv[i] >= 0) atomicAdd(&cnt[dv[i] >> BSHIFT], 1);
    }
    __syncthreads();
    for (int b = t; b < B; b += 256) {
        int c = cnt[b];
        int o = c ? atomicAdd(&bfill[b], c) : 0;
        off[b] = (b << CAPSHIFT) + o;
    }
    __syncthreads();
#pragma unroll
    for (int i = 0; i < PEB / 256; ++i) {
        int e = base + i * 256 + t;
        int d = dv[i];
        if (d >= 0) {
            int s = src[e];
            int slot = atomicAdd(&off[d >> BSHIFT], 1);
            packed[slot] = ((unsigned)s << BSHIFT) | (unsigned)(d & BMASK);
        }
    }
}

// ---------------------------------------------------------------- per-bucket CSR build
__global__ __launch_bounds__(256) void k_csrfill(const unsigned* __restrict__ packed,
                                                 const int* __restrict__ bfill,
                                                 int* __restrict__ colidx,
                                                 uint2* __restrict__ rowptr2,
                                                 float* __restrict__ dinv,
                                                 int N, int B) {
    __shared__ int ldeg[256];
    __shared__ int lscan[256];
    __shared__ int sexc[256];
    __shared__ int lfill[256];
    int t = threadIdx.x, bkt = blockIdx.x;
    int base = bkt << CAPSHIFT;
    int end  = base + bfill[bkt];
    ldeg[t] = 0;
    __syncthreads();
    for (int e = base + t; e < end; e += 256)
        atomicAdd(&ldeg[packed[e] & BMASK], 1);
    __syncthreads();
    int v = ldeg[t];
    lscan[t] = v;
    __syncthreads();
    for (int off = 1; off < 256; off <<= 1) {
        int x = (t >= off) ? lscan[t - off] : 0;
        __syncthreads();
        lscan[t] += x;
        __syncthreads();
    }
    int exc = lscan[t] - v;
    sexc[t] = exc;
    lfill[t] = 0;
    int node = (bkt << BSHIFT) + t;
    if (node < N) {
        rowptr2[node] = make_uint2((unsigned)(base + exc), (unsigned)(base + exc + v));
        dinv[node] = rsqrtf((float)v + 1.0f);
    }
    __syncthreads();
    for (int e = base + t; e < end; e += 256) {
        unsigned w = packed[e];
        int ld = w & BMASK;
        int pos = base + sexc[ld] + atomicAdd(&lfill[ld], 1);
        colidx[pos] = (int)(w >> BSHIFT);
    }
}

// ---------------------------------------------------------------- GEMM1: g1b = bf16((x @ W1) * dinv)
__global__ __launch_bounds__(256) void k_gemm1(const float* __restrict__ x,
                                               const float* __restrict__ W,
                                               const float* __restrict__ dinv,
                                               unsigned* __restrict__ g1b, int N) {
    __shared__ float xs[64 * 36];
    __shared__ float ws[32 * 64];
    int t = threadIdx.x;
    int row0 = blockIdx.x * 64;
    int tx = t & 15;
    int ty = t >> 4;
    int sr = t >> 3, sc = t & 7;

    float acc[4][4] = {};
    for (int kt = 0; kt < 4; ++kt) {
        const float4* W4 = (const float4*)(W + kt * 32 * HID_DIM);
        float4* ws4 = (float4*)ws;
        ws4[t] = W4[t];
        ws4[t + 256] = W4[t + 256];
#pragma unroll
        for (int half = 0; half < 2; ++half) {
            int r = sr + half * 32;
            int row = row0 + r;
            float4 val = make_float4(0.f, 0.f, 0.f, 0.f);
            if (row < N)
                val = *(const float4*)&x[(size_t)row * IN_DIM + kt * 32 + sc * 4];
            *(float4*)&xs[r * 36 + sc * 4] = val;
        }
        __syncthreads();
#pragma unroll
        for (int k = 0; k < 32; k += 4) {
            float a[4][4], b[4][4];
#pragma unroll
            for (int i = 0; i < 4; ++i)
                *(float4*)a[i] = *(const float4*)&xs[(ty * 4 + i) * 36 + k];
#pragma unroll
            for (int kk = 0; kk < 4; ++kk)
                *(float4*)b[kk] = *(const float4*)&ws[(k + kk) * HID_DIM + tx * 4];
#pragma unroll
            for (int i = 0; i < 4; ++i)
#pragma unroll
                for (int kk = 0; kk < 4; ++kk)
#pragma unroll
                    for (int j = 0; j < 4; ++j)
                        acc[i][j] += a[i][kk] * b[kk][j];
        }
        __syncthreads();
    }
#pragma unroll
    for (int i = 0; i < 4; ++i) {
        int row = row0 + ty * 4 + i;
        if (row < N) {
            float dv = dinv[row];
            uint2 u;
            u.x = pack_bf16x2(acc[i][0] * dv, acc[i][1] * dv);
            u.y = pack_bf16x2(acc[i][2] * dv, acc[i][3] * dv);
            *(uint2*)&g1b[(size_t)row * 32 + tx * 2] = u;
        }
    }
}

// ---------------------------------------------------------------- agg layer 1
// 128 threads = 2 waves; node per 16-lane quarter (4 nodes/wave).
// ql = lane&15: grp = ql>>3 (0..1), fp = ql&7. uint4 loads, 8 lanes/row.
// Loop step 4: 2 loads -> 4 edges in flight per node (16/wave).
// Reduce: single shfl_xor(8) (within the quarter).
__global__ __launch_bounds__(128) void k_agg1(const unsigned* __restrict__ g1,
                                              const uint2* __restrict__ rowptr2,
                                              const int* __restrict__ colidx,
                                              const float* __restrict__ dinv,
                                              const float* __restrict__ b1,
                                              unsigned* __restrict__ t1b, int N) {
    int t = threadIdx.x;
    int lane = t & 63;
    int q = lane >> 4, ql = lane & 15;
    int grp = ql >> 3, fp = ql & 7;
    int dd = blockIdx.x * 8 + (t >> 6) * 4 + q;
    bool live = dd < N;
    int d = live ? dd : N - 1;

    uint2 be = rowptr2[d];
    v2f a01 = {0.f, 0.f}, a23 = {0.f, 0.f}, a45 = {0.f, 0.f}, a67 = {0.f, 0.f};
#define ACC8V(qv)                                    \
    do {                                             \
        a01 += bfpair((qv).x); a23 += bfpair((qv).y);\
        a45 += bfpair((qv).z); a67 += bfpair((qv).w);\
    } while (0)
    int e = (int)be.x, end = (int)be.y;
    for (; e + 4 <= end; e += 4) {
        int s0 = colidx[e + grp];
        int s1 = colidx[e + 2 + grp];
        uint4 q0 = *(const uint4*)&g1[(size_t)s0 * 32 + fp * 4];
        uint4 q1 = *(const uint4*)&g1[(size_t)s1 * 32 + fp * 4];
        ACC8V(q0);
        ACC8V(q1);
    }
    for (; e + 2 <= end; e += 2) {
        int s = colidx[e + grp];
        uint4 qv = *(const uint4*)&g1[(size_t)s * 32 + fp * 4];
        ACC8V(qv);
    }
    if (e < end) {  // 1 edge left: grp 0 only
        int s = colidx[e];
        uint4 qv = *(const uint4*)&g1[(size_t)s * 32 + fp * 4];
        if (grp == 0) ACC8V(qv);
    }
#undef ACC8V
    float acc[8] = {a01.x, a01.y, a23.x, a23.y, a45.x, a45.y, a67.x, a67.y};
#pragma unroll
    for (int i = 0; i < 8; ++i)
        acc[i] += __shfl_xor(acc[i], 8);

    // self-loop + scale + bias + relu (per quarter)
    uint4 sq = *(const uint4*)&g1[(size_t)d * 32 + fp * 4];
    ACC8(sq);
    float dv = dinv[d];
    float4 bb0 = ((const float4*)b1)[fp * 2];
    float4 bb1 = ((const float4*)b1)[fp * 2 + 1];
    float v0 = fmaxf(dv * acc[0] + bb0.x, 0.f);
    float v1 = fmaxf(dv * acc[1] + bb0.y, 0.f);
    float v2 = fmaxf(dv * acc[2] + bb0.z, 0.f);
    float v3 = fmaxf(dv * acc[3] + bb0.w, 0.f);
    float v4 = fmaxf(dv * acc[4] + bb1.x, 0.f);
    float v5 = fmaxf(dv * acc[5] + bb1.y, 0.f);
    float v6 = fmaxf(dv * acc[6] + bb1.z, 0.f);
    float v7 = fmaxf(dv * acc[7] + bb1.w, 0.f);
    if (live && grp == 0) {
        uint4 u;
        u.x = pack_bf16x2(v0, v1);
        u.y = pack_bf16x2(v2, v3);
        u.z = pack_bf16x2(v4, v5);
        u.w = pack_bf16x2(v6, v7);
        *(uint4*)&t1b[(size_t)dd * 32 + fp * 4] = u;
    }
}

// ---------------------------------------------------------------- GEMM2: g2b = bf16((t1b @ W2) * dinv)
// gemm1-shape: 64 rows/block, t1 unpacked to fp32 at staging (t1s 64x68),
// 2x4 micro-tile, pure b128+fma loop, unroll 4.
__global__ __launch_bounds__(256) void k_gemm2b(const unsigned* __restrict__ t1b,
                                                const float* __restrict__ W2,
                                                const float* __restrict__ dinv,
                                                unsigned* __restrict__ g2b, int N) {
    __shared__ float t1s[64 * 68];            // fp32, stride 68
    __shared__ float W2s[HID_DIM * OUT_DIM];  // 8 KB
    int t = threadIdx.x;
    int row0 = blockIdx.x * 64;

    const float4* W24 = (const float4*)W2;  // 512 float4
    float4* W2s4 = (float4*)W2s;
    W2s4[t] = W24[t];
    W2s4[t + 256] = W24[t + 256];
#pragma unroll
    for (int i = 0; i < 8; ++i) {
        int idx = t + 256 * i;
        int r = idx >> 5, c = idx & 31;
        int grow = row0 + r;
        unsigned u = 0;
        if (grow < N) u = t1b[(size_t)grow * 32 + c];
        float2 f;
        f.x = BF_LO(u);
        f.y = BF_HI(u);
        *(float2*)&t1s[r * 68 + c * 2] = f;
    }
    __syncthreads();

    int ty = t >> 3;   // 32 groups x 2 rows
    int tx = t & 7;    // 8 groups x 4 cols
    float acc[2][4] = {};
#pragma unroll 4
    for (int k = 0; k < 64; k += 4) {
        float a[2][4], b[4][4];
#pragma unroll
        for (int i = 0; i < 2; ++i)
            *(float4*)a[i] = *(const float4*)&t1s[(ty * 2 + i) * 68 + k];
#pragma unroll
        for (int kk = 0; kk < 4; ++kk)
            *(float4*)b[kk] = *(const float4*)&W2s[(k + kk) * OUT_DIM + tx * 4];
#pragma unroll
        for (int i = 0; i < 2; ++i)
#pragma unroll
            for (int kk = 0; kk < 4; ++kk)
#pragma unroll
                for (int j = 0; j < 4; ++j)
                    acc[i][j] += a[i][kk] * b[kk][j];
    }
#pragma unroll
    for (int i = 0; i < 2; ++i) {
        int row = row0 + ty * 2 + i;
        if (row < N) {
            float dv = dinv[row];
            uint2 u;
            u.x = pack_bf16x2(acc[i][0] * dv, acc[i][1] * dv);
            u.y = pack_bf16x2(acc[i][2] * dv, acc[i][3] * dv);
            *(uint2*)&g2b[(size_t)row * 16 + tx * 2] = u;
        }
    }
}

// ---------------------------------------------------------------- agg layer 2
// 128 threads = 2 waves; node per 8-lane octet (8 nodes/wave).
// ol = lane&7: grp = ol>>2 (0..1), fp = ol&3. uint4 loads, 4 lanes/row.
// Loop step 4: 2 loads -> 4 edges in flight per node (32/wave).
// Reduce: single shfl_xor(4).
__global__ __launch_bounds__(128) void k_agg2(const unsigned* __restrict__ g2,
                                              const uint2* __restrict__ rowptr2,
                                              const int* __restrict__ colidx,
                                              const float* __restrict__ dinv,
                                              const float* __restrict__ b2,
                                              float* __restrict__ out, int N) {
    int t = threadIdx.x;
    int lane = t & 63;
    int o = lane >> 3, ol = lane & 7;
    int grp = ol >> 2, fp = ol & 3;
    int dd = blockIdx.x * 16 + (t >> 6) * 8 + o;
    bool live = dd < N;
    int d = live ? dd : N - 1;

    uint2 be = rowptr2[d];
    v2f a01 = {0.f, 0.f}, a23 = {0.f, 0.f}, a45 = {0.f, 0.f}, a67 = {0.f, 0.f};
#define ACC8V(qv)                                    \
    do {                                             \
        a01 += bfpair((qv).x); a23 += bfpair((qv).y);\
        a45 += bfpair((qv).z); a67 += bfpair((qv).w);\
    } while (0)
    int e = (int)be.x, end = (int)be.y;
    for (; e + 4 <= end; e += 4) {
        int s0 = colidx[e + grp];
        int s1 = colidx[e + 2 + grp];
        uint4 q0 = *(const uint4*)&g2[(size_t)s0 * 16 + fp * 4];
        uint4 q1 = *(const uint4*)&g2[(size_t)s1 * 16 + fp * 4];
        ACC8V(q0);
        ACC8V(q1);
    }
    for (; e + 2 <= end; e += 2) {
        int s = colidx[e + grp];
        uint4 qv = *(const uint4*)&g2[(size_t)s * 16 + fp * 4];
        ACC8V(qv);
    }
    if (e < end) {  // 1 edge left: grp 0 only
        int s = colidx[e];
        uint4 qv = *(const uint4*)&g2[(size_t)s * 16 + fp * 4];
        if (grp == 0) ACC8V(qv);
    }
#undef ACC8V
    float acc[8] = {a01.x, a01.y, a23.x, a23.y, a45.x, a45.y, a67.x, a67.y};
#pragma unroll
    for (int i = 0; i < 8; ++i)
        acc[i] += __shfl_xor(acc[i], 4);
    // self-loop + epilogue (per octet)
    uint4 sq = *(const uint4*)&g2[(size_t)d * 16 + fp * 4];
    ACC8(sq);
    float dv = dinv[d];
    float4 bb0 = ((const float4*)b2)[fp * 2];
    float4 bb1 = ((const float4*)b2)[fp * 2 + 1];
    if (live && grp == 0) {
        float4 r0, r1;
        r0.x = dv * acc[0] + bb0.x; r0.y = dv * acc[1] + bb0.y;
        r0.z = dv * acc[2] + bb0.z; r0.w = dv * acc[3] + bb0.w;
        r1.x = dv * acc[4] + bb1.x; r1.y = dv * acc[5] + bb1.y;
        r1.z = dv * acc[6] + bb1.z; r1.w = dv * acc[7] + bb1.w;
        *(float4*)&out[(size_t)dd * OUT_DIM + fp * 8] = r0;
        *(float4*)&out[(size_t)dd * OUT_DIM + fp * 8 + 4] = r1;
    }
}

// ---------------------------------------------------------------- launch
extern "C" void kernel_launch(void* const* d_in, const int* in_sizes, int n_in,
                              void* d_out, int out_size, void* d_ws, size_t ws_size,
                              hipStream_t stream) {
    const float* x  = (const float*)d_in[0];
    const int*   ei = (const int*)d_in[1];
    const float* W1 = (const float*)d_in[2];
    const float* b1 = (const float*)d_in[3];
    const float* W2 = (const float*)d_in[4];
    const float* b2 = (const float*)d_in[5];
    float* out = (float*)d_out;

    const int N = in_sizes[0] / IN_DIM;
    const int E = in_sizes[1] / 2;
    const int* src = ei;
    const int* dst = ei + E;

    const int B   = (N + BSIZE - 1) / BSIZE;          // buckets
    const int nPB = (E + PEB - 1) / PEB;              // partition blocks
    const size_t SLOTS = (size_t)B << CAPSHIFT;       // segmented edge slots

    char* p = (char*)d_ws;
    auto alloc = [&](size_t bytes) -> void* {
        void* r = (void*)p;
        p += (bytes + 255) & ~(size_t)255;
        return r;
    };
    int*      bfill   = (int*)alloc((size_t)B * 4);
    unsigned* packed  = (unsigned*)alloc(SLOTS * 4);
    int*      colidx  = (int*)alloc(SLOTS * 4);
    uint2*    rowptr2 = (uint2*)alloc((size_t)N * 8);
    float*    dinv    = (float*)alloc((size_t)N * 4);
    unsigned* g1b     = (unsigned*)alloc((size_t)N * 32 * 4);  // bf16x2 x 32/row
    unsigned* t1b     = (unsigned*)alloc((size_t)N * 32 * 4);  // bf16x2 x 32/row
    unsigned* g2b     = (unsigned*)alloc((size_t)N * 16 * 4);  // bf16x2 x 16/row

    hipMemsetAsync(bfill, 0, (size_t)B * 4, stream);
    k_partition<<<nPB, 256, 0, stream>>>(src, dst, E, bfill, packed, B);
    k_csrfill<<<B, 256, 0, stream>>>(packed, bfill, colidx, rowptr2, dinv, N, B);

    k_gemm1<<<(N + 63) / 64, 256, 0, stream>>>(x, W1, dinv, g1b, N);
    k_agg1<<<(N + 7) / 8, 128, 0, stream>>>(g1b, rowptr2, colidx, dinv, b1, t1b, N);
    k_gemm2b<<<(N + 63) / 64, 256, 0, stream>>>(t1b, W2, dinv, g2b, N);
    k_agg2<<<(N + 15) / 16, 128, 0, stream>>>(g2b, rowptr2, colidx, dinv, b2, out, N);
}

// Round 16
// 226.221 us; speedup vs baseline: 1.5064x; 1.0343x over previous
//
#include <hip/hip_runtime.h>
#include <hip/hip_bf16.h>

// 2-layer GCN (PyG GCNConv) on MI355X.
// R16: k_gemm1 -> bf16 MFMA (mfma_f32_16x16x32_bf16). R15 gemm1 was the last
// bulk-fp32-VALU kernel (2048 fma + 256 ds_b128 per thread, VALU 40%).
// Now: 16 rows/block staged to LDS bf16 (4.2KB, stride-66), wave w owns cols
// 16w..16w+15 (B-frags in VGPRs from L2-hot W1), 4 MFMA per wave = full K.
// Memory-floor bound (~51MB read + 13MB write). Everything else = R15.
// Layouts per guide: A[m=l&15][k=(l>>4)*8+j], B[k=(l>>4)*8+j][n=l&15],
// C/D col=lane&15, row=(lane>>4)*4+reg (m89-verified).

#define IN_DIM 128
#define HID_DIM 64
#define OUT_DIM 32
#define BSHIFT 8
#define BSIZE 256
#define BMASK 255
#define PEB 4096      // edges per partition block
#define CAPSHIFT 13   // 8192 slots per bucket segment (expected max ~4500)

typedef __attribute__((ext_vector_type(2))) float v2f;
typedef __attribute__((ext_vector_type(8))) short short8v;
typedef __attribute__((ext_vector_type(4))) float float4v;

__device__ inline unsigned pack_bf16x2(float a, float b) {
    unsigned ua = __float_as_uint(a), ub = __float_as_uint(b);
    unsigned ra = (ua + 0x7fffu + ((ua >> 16) & 1u)) >> 16;        // RNE
    unsigned rb = (ub + 0x7fffu + ((ub >> 16) & 1u)) & 0xffff0000u;
    return (ra & 0xffffu) | rb;
}
__device__ inline unsigned short f2bf(float f) {
    unsigned u = __float_as_uint(f);
    return (unsigned short)((u + 0x7fffu + ((u >> 16) & 1u)) >> 16);
}
#define BF_LO(w) __uint_as_float((w) << 16)
#define BF_HI(w) __uint_as_float((w) & 0xffff0000u)

__device__ inline v2f bfpair(unsigned u) {
    v2f r;
    r.x = __uint_as_float(u << 16);
    r.y = __uint_as_float(u & 0xffff0000u);
    return r;
}

#define ACC8(q)                                         \
    do {                                                \
        acc[0] += BF_LO((q).x); acc[1] += BF_HI((q).x); \
        acc[2] += BF_LO((q).y); acc[3] += BF_HI((q).y); \
        acc[4] += BF_LO((q).z); acc[5] += BF_HI((q).z); \
        acc[6] += BF_LO((q).w); acc[7] += BF_HI((q).w); \
    } while (0)

// ---------------------------------------------------------------- partition (single dispatch)
__global__ __launch_bounds__(256) void k_partition(const int* __restrict__ src,
                                                   const int* __restrict__ dst, int E,
                                                   int* __restrict__ bfill,
                                                   unsigned* __restrict__ packed, int B) {
    __shared__ int cnt[512];
    __shared__ int off[512];
    int t = threadIdx.x;
    for (int b = t; b < 512; b += 256) cnt[b] = 0;
    __syncthreads();
    int base = blockIdx.x * PEB;
    int dv[PEB / 256];  // cache dst values across passes
#pragma unroll
    for (int i = 0; i < PEB / 256; ++i) {
        int e = base + i * 256 + t;
        dv[i] = (e < E) ? dst[e] : -1;
        if (dv[i] >= 0) atomicAdd(&cnt[dv[i] >> BSHIFT], 1);
    }
    __syncthreads();
    for (int b = t; b < B; b += 256) {
        int c = cnt[b];
        int o = c ? atomicAdd(&bfill[b], c) : 0;
        off[b] = (b << CAPSHIFT) + o;
    }
    __syncthreads();
#pragma unroll
    for (int i = 0; i < PEB / 256; ++i) {
        int e = base + i * 256 + t;
        int d = dv[i];
        if (d >= 0) {
            int s = src[e];
            int slot = atomicAdd(&off[d >> BSHIFT], 1);
            packed[slot] = ((unsigned)s << BSHIFT) | (unsigned)(d & BMASK);
        }
    }
}

// ---------------------------------------------------------------- per-bucket CSR build
__global__ __launch_bounds__(256) void k_csrfill(const unsigned* __restrict__ packed,
                                                 const int* __restrict__ bfill,
                                                 int* __restrict__ colidx,
                                                 uint2* __restrict__ rowptr2,
                                                 float* __restrict__ dinv,
                                                 int N, int B) {
    __shared__ int ldeg[256];
    __shared__ int lscan[256];
    __shared__ int sexc[256];
    __shared__ int lfill[256];
    int t = threadIdx.x, bkt = blockIdx.x;
    int base = bkt << CAPSHIFT;
    int end  = base + bfill[bkt];
    ldeg[t] = 0;
    __syncthreads();
    for (int e = base + t; e < end; e += 256)
        atomicAdd(&ldeg[packed[e] & BMASK], 1);
    __syncthreads();
    int v = ldeg[t];
    lscan[t] = v;
    __syncthreads();
    for (int off = 1; off < 256; off <<= 1) {
        int x = (t >= off) ? lscan[t - off] : 0;
        __syncthreads();
        lscan[t] += x;
        __syncthreads();
    }
    int exc = lscan[t] - v;
    sexc[t] = exc;
    lfill[t] = 0;
    int node = (bkt << BSHIFT) + t;
    if (node < N) {
        rowptr2[node] = make_uint2((unsigned)(base + exc), (unsigned)(base + exc + v));
        dinv[node] = rsqrtf((float)v + 1.0f);
    }
    __syncthreads();
    for (int e = base + t; e < end; e += 256) {
        unsigned w = packed[e];
        int ld = w & BMASK;
        int pos = base + sexc[ld] + atomicAdd(&lfill[ld], 1);
        colidx[pos] = (int)(w >> BSHIFT);
    }
}

// ---------------------------------------------------------------- GEMM1 (MFMA): g1b = bf16((x @ W1) * dinv)
// 16 rows/block, 256 threads = 4 waves. Wave w -> cols 16w..16w+15.
// x tile staged to LDS as bf16x2, row stride 66 uints. B-frags from global
// (L2-hot W1). 4 x mfma_f32_16x16x32_bf16 per wave = full K=128.
__global__ __launch_bounds__(256) void k_gemm1(const float* __restrict__ x,
                                               const float* __restrict__ W,
                                               const float* __restrict__ dinv,
                                               unsigned* __restrict__ g1b, int N) {
    __shared__ unsigned xs[16 * 66];  // 4.2 KB
    int t = threadIdx.x;
    int row0 = blockIdx.x * 16;
    int w = t >> 6, lane = t & 63;
    int quad = lane >> 4, m = lane & 15;
    int ncol = w * 16 + m;

    // B-frags: bfrag[kt] element j = W[(kt*32 + quad*8 + j)*64 + ncol]
    union { unsigned u[4]; short8v s; } bf[4];
#pragma unroll
    for (int kt = 0; kt < 4; ++kt) {
#pragma unroll
        for (int jp = 0; jp < 4; ++jp) {
            int k0 = kt * 32 + quad * 8 + jp * 2;
            float f0 = W[(size_t)k0 * HID_DIM + ncol];
            float f1 = W[(size_t)(k0 + 1) * HID_DIM + ncol];
            bf[kt].u[jp] = pack_bf16x2(f0, f1);
        }
    }

    // stage x tile (16 rows x 128 fp32 -> bf16x2): 512 float4, 2 per thread
#pragma unroll
    for (int i = 0; i < 2; ++i) {
        int idx = t + 256 * i;
        int r = idx >> 5, c4 = idx & 31;
        int grow = row0 + r;
        float4 f = make_float4(0.f, 0.f, 0.f, 0.f);
        if (grow < N) f = ((const float4*)x)[(size_t)grow * 32 + c4];
        xs[r * 66 + c4 * 2]     = pack_bf16x2(f.x, f.y);
        xs[r * 66 + c4 * 2 + 1] = pack_bf16x2(f.z, f.w);
    }
    __syncthreads();

    float4v acc = {0.f, 0.f, 0.f, 0.f};
#pragma unroll
    for (int kt = 0; kt < 4; ++kt) {
        union { unsigned u[4]; short8v s; } af;
        const unsigned* ap = &xs[m * 66 + kt * 16 + quad * 4];
        af.u[0] = ap[0]; af.u[1] = ap[1]; af.u[2] = ap[2]; af.u[3] = ap[3];
        acc = __builtin_amdgcn_mfma_f32_16x16x32_bf16(af.s, bf[kt].s, acc, 0, 0, 0);
    }

    // epilogue: lane holds D[row = quad*4+reg][col = ncol]
    unsigned short* g1s = (unsigned short*)g1b;
#pragma unroll
    for (int reg = 0; reg < 4; ++reg) {
        int r = row0 + quad * 4 + reg;
        if (r < N) {
            float dv = dinv[r];
            g1s[(size_t)r * HID_DIM + ncol] = f2bf(acc[reg] * dv);
        }
    }
}

// ---------------------------------------------------------------- agg layer 1
// 128 threads = 2 waves; node per 16-lane quarter (4 nodes/wave).
__global__ __launch_bounds__(128) void k_agg1(const unsigned* __restrict__ g1,
                                              const uint2* __restrict__ rowptr2,
                                              const int* __restrict__ colidx,
                                              const float* __restrict__ dinv,
                                              const float* __restrict__ b1,
                                              unsigned* __restrict__ t1b, int N) {
    int t = threadIdx.x;
    int lane = t & 63;
    int q = lane >> 4, ql = lane & 15;
    int grp = ql >> 3, fp = ql & 7;
    int dd = blockIdx.x * 8 + (t >> 6) * 4 + q;
    bool live = dd < N;
    int d = live ? dd : N - 1;

    uint2 be = rowptr2[d];
    v2f a01 = {0.f, 0.f}, a23 = {0.f, 0.f}, a45 = {0.f, 0.f}, a67 = {0.f, 0.f};
#define ACC8V(qv)                                    \
    do {                                             \
        a01 += bfpair((qv).x); a23 += bfpair((qv).y);\
        a45 += bfpair((qv).z); a67 += bfpair((qv).w);\
    } while (0)
    int e = (int)be.x, end = (int)be.y;
    for (; e + 4 <= end; e += 4) {
        int s0 = colidx[e + grp];
        int s1 = colidx[e + 2 + grp];
        uint4 q0 = *(const uint4*)&g1[(size_t)s0 * 32 + fp * 4];
        uint4 q1 = *(const uint4*)&g1[(size_t)s1 * 32 + fp * 4];
        ACC8V(q0);
        ACC8V(q1);
    }
    for (; e + 2 <= end; e += 2) {
        int s = colidx[e + grp];
        uint4 qv = *(const uint4*)&g1[(size_t)s * 32 + fp * 4];
        ACC8V(qv);
    }
    if (e < end) {  // 1 edge left: grp 0 only
        int s = colidx[e];
        uint4 qv = *(const uint4*)&g1[(size_t)s * 32 + fp * 4];
        if (grp == 0) ACC8V(qv);
    }
#undef ACC8V
    float acc[8] = {a01.x, a01.y, a23.x, a23.y, a45.x, a45.y, a67.x, a67.y};
#pragma unroll
    for (int i = 0; i < 8; ++i)
        acc[i] += __shfl_xor(acc[i], 8);

    // self-loop + scale + bias + relu (per quarter)
    uint4 sq = *(const uint4*)&g1[(size_t)d * 32 + fp * 4];
    ACC8(sq);
    float dv = dinv[d];
    float4 bb0 = ((const float4*)b1)[fp * 2];
    float4 bb1 = ((const float4*)b1)[fp * 2 + 1];
    float v0 = fmaxf(dv * acc[0] + bb0.x, 0.f);
    float v1 = fmaxf(dv * acc[1] + bb0.y, 0.f);
    float v2 = fmaxf(dv * acc[2] + bb0.z, 0.f);
    float v3 = fmaxf(dv * acc[3] + bb0.w, 0.f);
    float v4 = fmaxf(dv * acc[4] + bb1.x, 0.f);
    float v5 = fmaxf(dv * acc[5] + bb1.y, 0.f);
    float v6 = fmaxf(dv * acc[6] + bb1.z, 0.f);
    float v7 = fmaxf(dv * acc[7] + bb1.w, 0.f);
    if (live && grp == 0) {
        uint4 u;
        u.x = pack_bf16x2(v0, v1);
        u.y = pack_bf16x2(v2, v3);
        u.z = pack_bf16x2(v4, v5);
        u.w = pack_bf16x2(v6, v7);
        *(uint4*)&t1b[(size_t)dd * 32 + fp * 4] = u;
    }
}

// ---------------------------------------------------------------- GEMM2: g2b = bf16((t1b @ W2) * dinv)
// gemm1-shape: 64 rows/block, t1 unpacked to fp32 at staging (t1s 64x68),
// 2x4 micro-tile, pure b128+fma loop, unroll 4.
__global__ __launch_bounds__(256) void k_gemm2b(const unsigned* __restrict__ t1b,
                                                const float* __restrict__ W2,
                                                const float* __restrict__ dinv,
                                                unsigned* __restrict__ g2b, int N) {
    __shared__ float t1s[64 * 68];            // fp32, stride 68
    __shared__ float W2s[HID_DIM * OUT_DIM];  // 8 KB
    int t = threadIdx.x;
    int row0 = blockIdx.x * 64;

    const float4* W24 = (const float4*)W2;  // 512 float4
    float4* W2s4 = (float4*)W2s;
    W2s4[t] = W24[t];
    W2s4[t + 256] = W24[t + 256];
#pragma unroll
    for (int i = 0; i < 8; ++i) {
        int idx = t + 256 * i;
        int r = idx >> 5, c = idx & 31;
        int grow = row0 + r;
        unsigned u = 0;
        if (grow < N) u = t1b[(size_t)grow * 32 + c];
        float2 f;
        f.x = BF_LO(u);
        f.y = BF_HI(u);
        *(float2*)&t1s[r * 68 + c * 2] = f;
    }
    __syncthreads();

    int ty = t >> 3;   // 32 groups x 2 rows
    int tx = t & 7;    // 8 groups x 4 cols
    float acc[2][4] = {};
#pragma unroll 4
    for (int k = 0; k < 64; k += 4) {
        float a[2][4], b[4][4];
#pragma unroll
        for (int i = 0; i < 2; ++i)
            *(float4*)a[i] = *(const float4*)&t1s[(ty * 2 + i) * 68 + k];
#pragma unroll
        for (int kk = 0; kk < 4; ++kk)
            *(float4*)b[kk] = *(const float4*)&W2s[(k + kk) * OUT_DIM + tx * 4];
#pragma unroll
        for (int i = 0; i < 2; ++i)
#pragma unroll
            for (int kk = 0; kk < 4; ++kk)
#pragma unroll
                for (int j = 0; j < 4; ++j)
                    acc[i][j] += a[i][kk] * b[kk][j];
    }
#pragma unroll
    for (int i = 0; i < 2; ++i) {
        int row = row0 + ty * 2 + i;
        if (row < N) {
            float dv = dinv[row];
            uint2 u;
            u.x = pack_bf16x2(acc[i][0] * dv, acc[i][1] * dv);
            u.y = pack_bf16x2(acc[i][2] * dv, acc[i][3] * dv);
            *(uint2*)&g2b[(size_t)row * 16 + tx * 2] = u;
        }
    }
}

// ---------------------------------------------------------------- agg layer 2
// 128 threads = 2 waves; node per 8-lane octet (8 nodes/wave).
__global__ __launch_bounds__(128) void k_agg2(const unsigned* __restrict__ g2,
                                              const uint2* __restrict__ rowptr2,
                                              const int* __restrict__ colidx,
                                              const float* __restrict__ dinv,
                                              const float* __restrict__ b2,
                                              float* __restrict__ out, int N) {
    int t = threadIdx.x;
    int lane = t & 63;
    int o = lane >> 3, ol = lane & 7;
    int grp = ol >> 2, fp = ol & 3;
    int dd = blockIdx.x * 16 + (t >> 6) * 8 + o;
    bool live = dd < N;
    int d = live ? dd : N - 1;

    uint2 be = rowptr2[d];
    v2f a01 = {0.f, 0.f}, a23 = {0.f, 0.f}, a45 = {0.f, 0.f}, a67 = {0.f, 0.f};
#define ACC8V(qv)                                    \
    do {                                             \
        a01 += bfpair((qv).x); a23 += bfpair((qv).y);\
        a45 += bfpair((qv).z); a67 += bfpair((qv).w);\
    } while (0)
    int e = (int)be.x, end = (int)be.y;
    for (; e + 4 <= end; e += 4) {
        int s0 = colidx[e + grp];
        int s1 = colidx[e + 2 + grp];
        uint4 q0 = *(const uint4*)&g2[(size_t)s0 * 16 + fp * 4];
        uint4 q1 = *(const uint4*)&g2[(size_t)s1 * 16 + fp * 4];
        ACC8V(q0);
        ACC8V(q1);
    }
    for (; e + 2 <= end; e += 2) {
        int s = colidx[e + grp];
        uint4 qv = *(const uint4*)&g2[(size_t)s * 16 + fp * 4];
        ACC8V(qv);
    }
    if (e < end) {  // 1 edge left: grp 0 only
        int s = colidx[e];
        uint4 qv = *(const uint4*)&g2[(size_t)s * 16 + fp * 4];
        if (grp == 0) ACC8V(qv);
    }
#undef ACC8V
    float acc[8] = {a01.x, a01.y, a23.x, a23.y, a45.x, a45.y, a67.x, a67.y};
#pragma unroll
    for (int i = 0; i < 8; ++i)
        acc[i] += __shfl_xor(acc[i], 4);
    // self-loop + epilogue (per octet)
    uint4 sq = *(const uint4*)&g2[(size_t)d * 16 + fp * 4];
    ACC8(sq);
    float dv = dinv[d];
    float4 bb0 = ((const float4*)b2)[fp * 2];
    float4 bb1 = ((const float4*)b2)[fp * 2 + 1];
    if (live && grp == 0) {
        float4 r0, r1;
        r0.x = dv * acc[0] + bb0.x; r0.y = dv * acc[1] + bb0.y;
        r0.z = dv * acc[2] + bb0.z; r0.w = dv * acc[3] + bb0.w;
        r1.x = dv * acc[4] + bb1.x; r1.y = dv * acc[5] + bb1.y;
        r1.z = dv * acc[6] + bb1.z; r1.w = dv * acc[7] + bb1.w;
        *(float4*)&out[(size_t)dd * OUT_DIM + fp * 8] = r0;
        *(float4*)&out[(size_t)dd * OUT_DIM + fp * 8 + 4] = r1;
    }
}

// ---------------------------------------------------------------- launch
extern "C" void kernel_launch(void* const* d_in, const int* in_sizes, int n_in,
                              void* d_out, int out_size, void* d_ws, size_t ws_size,
                              hipStream_t stream) {
    const float* x  = (const float*)d_in[0];
    const int*   ei = (const int*)d_in[1];
    const float* W1 = (const float*)d_in[2];
    const float* b1 = (const float*)d_in[3];
    const float* W2 = (const float*)d_in[4];
    const float* b2 = (const float*)d_in[5];
    float* out = (float*)d_out;

    const int N = in_sizes[0] / IN_DIM;
    const int E = in_sizes[1] / 2;
    const int* src = ei;
    const int* dst = ei + E;

    const int B   = (N + BSIZE - 1) / BSIZE;          // buckets
    const int nPB = (E + PEB - 1) / PEB;              // partition blocks
    const size_t SLOTS = (size_t)B << CAPSHIFT;       // segmented edge slots

    char* p = (char*)d_ws;
    auto alloc = [&](size_t bytes) -> void* {
        void* r = (void*)p;
        p += (bytes + 255) & ~(size_t)255;
        return r;
    };
    int*      bfill   = (int*)alloc((size_t)B * 4);
    unsigned* packed  = (unsigned*)alloc(SLOTS * 4);
    int*      colidx  = (int*)alloc(SLOTS * 4);
    uint2*    rowptr2 = (uint2*)alloc((size_t)N * 8);
    float*    dinv    = (float*)alloc((size_t)N * 4);
    unsigned* g1b     = (unsigned*)alloc((size_t)N * 32 * 4);  // bf16x2 x 32/row
    unsigned* t1b     = (unsigned*)alloc((size_t)N * 32 * 4);  // bf16x2 x 32/row
    unsigned* g2b     = (unsigned*)alloc((size_t)N * 16 * 4);  // bf16x2 x 16/row

    hipMemsetAsync(bfill, 0, (size_t)B * 4, stream);
    k_partition<<<nPB, 256, 0, stream>>>(src, dst, E, bfill, packed, B);
    k_csrfill<<<B, 256, 0, stream>>>(packed, bfill, colidx, rowptr2, dinv, N, B);

    k_gemm1<<<(N + 15) / 16, 256, 0, stream>>>(x, W1, dinv, g1b, N);
    k_agg1<<<(N + 7) / 8, 128, 0, stream>>>(g1b, rowptr2, colidx, dinv, b1, t1b, N);
    k_gemm2b<<<(N + 63) / 64, 256, 0, stream>>>(t1b, W2, dinv, g2b, N);
    k_agg2<<<(N + 15) / 16, 128, 0, stream>>>(g2b, rowptr2, colidx, dinv, b2, out, N);
}